// Round 5
// baseline (325.754 us; speedup 1.0000x reference)
//
#include <hip/hip_runtime.h>

#define H 2048
#define NH 16
#define NKV 4
#define HD 128
#define CTX 8192
#define IDIM 8192
#define EPS 1e-6f
#define SCALE 0.08838834764831845f

__device__ __forceinline__ float wave_sum(float x){
#pragma unroll
    for(int o=32;o>0;o>>=1) x += __shfl_xor(x,o,64);
    return x;
}
__device__ __forceinline__ float wave_max(float x){
#pragma unroll
    for(int o=32;o>0;o>>=1) x = fmaxf(x,__shfl_xor(x,o,64));
    return x;
}
__device__ __forceinline__ void keep4(const float4& v){
    asm volatile("" :: "v"(v.x), "v"(v.y), "v"(v.z), "v"(v.w));
}
// Async global->LDS stage: 16B/lane, fire-and-forget (no dest VGPRs). Dest =
// uniform base + lane*16. Drained by the vmcnt(0) at __syncthreads().
__device__ __forceinline__ void stage16(const float* g, float* l){
    __builtin_amdgcn_global_load_lds(
        (const __attribute__((address_space(1))) void*)g,
        (__attribute__((address_space(3))) void*)l, 16, 0, 0);
}

// ---------- K1: persistent ln1-RMSNorm + QKV matvec. grid 576 x 256 ----------
// Norm computed ONCE per block (was 1280 redundant copies -> 576), then 2
// row-groups of 4 rows each, LDS-staged. Saves ~11MB of xres/ln1 re-reads.
__global__ __launch_bounds__(256,4) void k_qkv(const float* __restrict__ Wq,
                                               const float* __restrict__ Wk,
                                               const float* __restrict__ Wv,
                                               const float* __restrict__ hs,
                                               const float* __restrict__ ln1,
                                               float* __restrict__ qg,
                                               float* __restrict__ kvec,
                                               float* __restrict__ vvec){
    __shared__ __align__(16) float hw[H];
    __shared__ __align__(16) float wlds[4*2048];   // 32KB: one row per wave
    __shared__ float red[4];
    int tid = threadIdx.x, wid = tid>>6, lane = tid&63;

    // small vector loads first
    float4 a = *(const float4*)(hs + tid*8);
    float4 b = *(const float4*)(hs + tid*8 + 4);
    float4 wa = *(const float4*)(ln1 + tid*8);
    float4 wb = *(const float4*)(ln1 + tid*8 + 4);

    // prologue: stage group-0 weight row (hidden under the norm phase)
    {
        int row = blockIdx.x*8 + wid;
        const float* wr = (row < 4096) ? (Wq + (size_t)row*H)
                        : (row < 4608) ? (Wk + (size_t)(row-4096)*H)
                                       : (Wv + (size_t)(row-4608)*H);
#pragma unroll
        for(int i=0;i<8;i++) stage16(wr + i*256 + lane*4, wlds + wid*2048 + i*256);
    }

    float ss = a.x*a.x+a.y*a.y+a.z*a.z+a.w*a.w + b.x*b.x+b.y*b.y+b.z*b.z+b.w*b.w;
    ss = wave_sum(ss);
    if(lane==0) red[wid] = ss;
    __syncthreads();
    float rs = rsqrtf((red[0]+red[1]+red[2]+red[3])/(float)H + EPS);
    *(float4*)(hw + tid*8)     = make_float4(a.x*rs*wa.x, a.y*rs*wa.y, a.z*rs*wa.z, a.w*rs*wa.w);
    *(float4*)(hw + tid*8 + 4) = make_float4(b.x*rs*wb.x, b.y*rs*wb.y, b.z*rs*wb.z, b.w*rs*wb.w);
    __syncthreads();   // also drains group-0 staging

    for(int t=0;t<2;t++){
        if(t){
            __syncthreads();   // group t-1 LDS reads fully retired before overwrite
            int row = blockIdx.x*8 + t*4 + wid;
            const float* wr = (row < 4096) ? (Wq + (size_t)row*H)
                            : (row < 4608) ? (Wk + (size_t)(row-4096)*H)
                                           : (Wv + (size_t)(row-4608)*H);
#pragma unroll
            for(int i=0;i<8;i++) stage16(wr + i*256 + lane*4, wlds + wid*2048 + i*256);
            __syncthreads();   // drain
        }
        int row = blockIdx.x*8 + t*4 + wid;
        float* op = (row < 4096) ? (qg + row)
                  : (row < 4608) ? (kvec + (row-4096))
                                 : (vvec + (row-4608));
        float acc = 0.f;
#pragma unroll
        for(int i=0;i<8;i++){
            float4 rv = *(const float4*)(wlds + wid*2048 + i*256 + lane*4);
            float4 hv = *(const float4*)(hw + i*256 + lane*4);
            acc += rv.x*hv.x + rv.y*hv.y + rv.z*hv.z + rv.w*hv.w;
        }
        acc = wave_sum(acc);
        if(lane==0) *op = acc;
    }
}

// ---------- K2: q/k RMS + RoPE + gate sigmoid. grid 20 x 64 ----------
__global__ __launch_bounds__(64) void k_rope(const float* __restrict__ qg,
                                             const float* __restrict__ kvec,
                                             const float* __restrict__ vvec,
                                             const int* __restrict__ pos,
                                             const float* __restrict__ qn,
                                             const float* __restrict__ kn,
                                             const float* __restrict__ rc,
                                             const float* __restrict__ rsn,
                                             float* __restrict__ q_rope,
                                             float* __restrict__ gate_sig,
                                             float* __restrict__ knew,
                                             float* __restrict__ vnew){
    int b = blockIdx.x, lane = threadIdx.x;
    int p = pos[0];
    float c = rc[(size_t)p*64 + lane];
    float s = rsn[(size_t)p*64 + lane];
    if(b < NH){
        int h = b;
        float x1 = qg[h*256 + lane], x2 = qg[h*256 + 64 + lane];
        float ssq = wave_sum(x1*x1 + x2*x2);
        float r = rsqrtf(ssq/128.f + EPS);
        float n1 = x1*r*qn[lane];
        float n2 = x2*r*qn[lane+64];
        q_rope[h*128 + lane]      = n1*c - n2*s;
        q_rope[h*128 + 64 + lane] = n2*c + n1*s;
        float g1 = qg[h*256 + 128 + lane], g2 = qg[h*256 + 192 + lane];
        gate_sig[h*128 + lane]      = 1.f/(1.f + __expf(-g1));
        gate_sig[h*128 + 64 + lane] = 1.f/(1.f + __expf(-g2));
    } else {
        int j = b - NH;
        float x1 = kvec[j*128 + lane], x2 = kvec[j*128 + 64 + lane];
        float ssq = wave_sum(x1*x1 + x2*x2);
        float r = rsqrtf(ssq/128.f + EPS);
        float n1 = x1*r*kn[lane];
        float n2 = x2*r*kn[lane+64];
        knew[j*128 + lane]      = n1*c - n2*s;
        knew[j*128 + 64 + lane] = n2*c + n1*s;
        vnew[j*128 + lane]      = vvec[j*128 + lane];
        vnew[j*128 + 64 + lane] = vvec[j*128 + 64 + lane];
    }
}

// ---------- K3: flash-decode partials. grid (nchunk, NKV) x 128 ----------
// (unchanged this round — isolate the persistent-matvec experiments)
__global__ __launch_bounds__(128) void k_attn_part(const float* __restrict__ cache,
                                                   const float* __restrict__ q_rope,
                                                   const float* __restrict__ mask,
                                                   const int* __restrict__ pos,
                                                   const float* __restrict__ knew,
                                                   const float* __restrict__ vnew,
                                                   float* __restrict__ part_m,
                                                   float* __restrict__ part_l,
                                                   float* __restrict__ part_o,
                                                   int nchunk, int chunk){
    int j = blockIdx.y, ci = blockIdx.x, tid = threadIdx.x;
    int p = pos[0];
    __shared__ float q_s[512];
    __shared__ float s_s[512];
    __shared__ float m_s[4], l_s[4], mt_s[4], lt_s[4];
#pragma unroll
    for(int t=0;t<4;t++) q_s[t*128 + tid] = q_rope[j*512 + t*128 + tid];
    if(tid < 4){ m_s[tid] = -3.0e38f; l_s[tid] = 0.f; }
    float o0=0.f,o1=0.f,o2=0.f,o3=0.f;
    __syncthreads();
    int base0 = ci*chunk;
    for(int s0=0; s0<chunk; s0+=128){
        int c = base0 + s0 + tid;
        const float* kr = (c==p) ? (knew + (size_t)j*HD)
                                 : (cache + ((size_t)j*CTX + c)*HD);
        float a0=0.f,a1=0.f,a2=0.f,a3=0.f;
        for(int d0=0; d0<HD; d0+=32){
            float4 u8[8];
#pragma unroll
            for(int t=0;t<8;t++) u8[t] = *(const float4*)(kr + d0 + t*4);
#pragma unroll
            for(int t=0;t<8;t++) keep4(u8[t]);
#pragma unroll
            for(int t=0;t<8;t++){
                int dd = d0 + t*4;
                const float* q0=q_s+dd; const float* q1=q_s+128+dd;
                const float* q2=q_s+256+dd; const float* q3=q_s+384+dd;
                a0 += q0[0]*u8[t].x+q0[1]*u8[t].y+q0[2]*u8[t].z+q0[3]*u8[t].w;
                a1 += q1[0]*u8[t].x+q1[1]*u8[t].y+q1[2]*u8[t].z+q1[3]*u8[t].w;
                a2 += q2[0]*u8[t].x+q2[1]*u8[t].y+q2[2]*u8[t].z+q2[3]*u8[t].w;
                a3 += q3[0]*u8[t].x+q3[1]*u8[t].y+q3[2]*u8[t].z+q3[3]*u8[t].w;
            }
        }
        float mv = mask[c];
        s_s[tid]       = a0*SCALE + mv;
        s_s[128 + tid] = a1*SCALE + mv;
        s_s[256 + tid] = a2*SCALE + mv;
        s_s[384 + tid] = a3*SCALE + mv;
        __syncthreads();
        int wid = tid>>6, lane = tid&63;
#pragma unroll
        for(int hh=0; hh<2; hh++){
            int h = wid*2 + hh;
            float v0 = s_s[h*128 + lane], v1 = s_s[h*128 + 64 + lane];
            float m = wave_max(fmaxf(v0, v1));
            float l = wave_sum(__expf(v0 - m) + __expf(v1 - m));
            if(lane==0){ mt_s[h]=m; lt_s[h]=l; }
        }
        __syncthreads();
        float mn[4], sc_old[4];
#pragma unroll
        for(int h=0;h<4;h++){
            mn[h] = fmaxf(m_s[h], mt_s[h]);
            sc_old[h] = __expf(m_s[h] - mn[h]);
        }
        float w0 = __expf(s_s[tid]       - mn[0]);
        float w1 = __expf(s_s[128 + tid] - mn[1]);
        float w2 = __expf(s_s[256 + tid] - mn[2]);
        float w3 = __expf(s_s[384 + tid] - mn[3]);
        __syncthreads();
        s_s[tid]=w0; s_s[128+tid]=w1; s_s[256+tid]=w2; s_s[384+tid]=w3;
        if(tid < 4){
            l_s[tid] = l_s[tid]*sc_old[tid] + lt_s[tid]*__expf(mt_s[tid] - mn[tid]);
            m_s[tid] = mn[tid];
        }
        __syncthreads();
        o0 *= sc_old[0]; o1 *= sc_old[1]; o2 *= sc_old[2]; o3 *= sc_old[3];
        const float* vb = cache + (size_t)NKV*CTX*HD + ((size_t)j*CTX + base0 + s0)*HD;
        for(int cc0=0; cc0<128; cc0+=16){
            float v[16];
#pragma unroll
            for(int t=0;t<16;t++){
                int gpos = base0 + s0 + cc0 + t;   // wave-uniform select
                const float* vrow = (gpos==p) ? (vnew + (size_t)j*HD)
                                              : (vb + (size_t)(cc0+t)*HD);
                v[t] = vrow[tid];
            }
            asm volatile("" :: "v"(v[0]),  "v"(v[1]),  "v"(v[2]),  "v"(v[3]),
                              "v"(v[4]),  "v"(v[5]),  "v"(v[6]),  "v"(v[7]),
                              "v"(v[8]),  "v"(v[9]),  "v"(v[10]), "v"(v[11]),
                              "v"(v[12]), "v"(v[13]), "v"(v[14]), "v"(v[15]));
#pragma unroll
            for(int t=0;t<16;t++){
                int cc = cc0 + t;
                o0 += s_s[cc]*v[t];
                o1 += s_s[128+cc]*v[t];
                o2 += s_s[256+cc]*v[t];
                o3 += s_s[384+cc]*v[t];
            }
        }
        __syncthreads();
    }
    int h0 = j*4;
    part_o[((size_t)(h0+0)*nchunk + ci)*128 + tid] = o0;
    part_o[((size_t)(h0+1)*nchunk + ci)*128 + tid] = o1;
    part_o[((size_t)(h0+2)*nchunk + ci)*128 + tid] = o2;
    part_o[((size_t)(h0+3)*nchunk + ci)*128 + tid] = o3;
    if(tid < 4){
        part_m[(h0+tid)*nchunk + ci] = m_s[tid];
        part_l[(h0+tid)*nchunk + ci] = l_s[tid];
    }
}

// ---------- K4: combine chunks + gate. grid 16 x 128 ----------
__global__ __launch_bounds__(128) void k_attn_red(const float* __restrict__ part_m,
                                                  const float* __restrict__ part_l,
                                                  const float* __restrict__ part_o,
                                                  const float* __restrict__ gate_sig,
                                                  float* __restrict__ attn,
                                                  int nchunk){
    int h = blockIdx.x, d = threadIdx.x;
    float mg = -3.0e38f;
    for(int i=0;i<nchunk;i++) mg = fmaxf(mg, part_m[h*nchunk + i]);
    float lg = 0.f, oa = 0.f;
    for(int i=0;i<nchunk;i++){
        float e = __expf(part_m[h*nchunk + i] - mg);
        lg += part_l[h*nchunk + i]*e;
        oa += e*part_o[((size_t)h*nchunk + i)*128 + d];
    }
    attn[h*128 + d] = oa/lg * gate_sig[h*128 + d];
}

// ---------- K5: Wo matvec + residual, LDS-staged. grid 512 x 256 ----------
__global__ __launch_bounds__(256,4) void k_wo(const float* __restrict__ Wo,
                                              const float* __restrict__ attn,
                                              const float* __restrict__ resid,
                                              float* __restrict__ x){
    __shared__ __align__(16) float wlds[4*2048];   // 32KB: one row per wave
    int tid = threadIdx.x, wid = tid>>6, lane = tid&63;
    int row = blockIdx.x*4 + wid;
    const float* wr = Wo + (size_t)row*H;
    // activation loads first (register-resident, small)
    float4 hv[8];
#pragma unroll
    for(int i=0;i<8;i++) hv[i] = *(const float4*)(attn + i*256 + lane*4);
    // async-stage the weight row
#pragma unroll
    for(int i=0;i<8;i++) stage16(wr + i*256 + lane*4, wlds + wid*2048 + i*256);
    __syncthreads();
    float acc = 0.f;
#pragma unroll
    for(int i=0;i<8;i++){
        float4 rv = *(const float4*)(wlds + wid*2048 + i*256 + lane*4);
        acc += rv.x*hv[i].x + rv.y*hv[i].y + rv.z*hv[i].z + rv.w*hv[i].w;
    }
    acc = wave_sum(acc);
    if(lane==0) x[row] = resid[row] + acc;
}

// ---------- K6: persistent ln2-RMSNorm + gate/up matvec + SiLU. grid 512 x 256 ----------
// Norm once per block (was 2048 redundant copies -> 512, saves ~24MB of reads),
// then 4 row-groups of 4 outputs each; each wave stages its own g+u rows (16KB).
__global__ __launch_bounds__(256,2) void k_gateup(const float* __restrict__ Wg,
                                                  const float* __restrict__ Wu,
                                                  const float* __restrict__ xres,
                                                  const float* __restrict__ ln2,
                                                  float* __restrict__ act){
    __shared__ __align__(16) float hw[H];
    __shared__ __align__(16) float wlds[4*4096];   // 64KB: g-row + u-row per wave
    __shared__ float red[4];
    int tid = threadIdx.x, wid = tid>>6, lane = tid&63;

    // small vector loads first
    float4 a = *(const float4*)(xres + (size_t)tid*8);
    float4 b = *(const float4*)(xres + (size_t)tid*8 + 4);
    float4 wa = *(const float4*)(ln2 + (size_t)tid*8);
    float4 wb = *(const float4*)(ln2 + (size_t)tid*8 + 4);

    // prologue: stage group-0 rows (hidden under the norm phase)
    {
        int row = blockIdx.x*16 + wid;
        const float* gr = Wg + (size_t)row*H;
        const float* ur = Wu + (size_t)row*H;
#pragma unroll
        for(int i=0;i<8;i++) stage16(gr + i*256 + lane*4, wlds + wid*4096 + i*256);
#pragma unroll
        for(int i=0;i<8;i++) stage16(ur + i*256 + lane*4, wlds + wid*4096 + 2048 + i*256);
    }

    float x[8] = {a.x,a.y,a.z,a.w,b.x,b.y,b.z,b.w};
    float ss = 0.f;
#pragma unroll
    for(int i=0;i<8;i++) ss += x[i]*x[i];
    ss = wave_sum(ss);
    if(lane==0) red[wid] = ss;
    __syncthreads();
    float tot = red[0]+red[1]+red[2]+red[3];
    float rs = rsqrtf(tot/(float)H + EPS);
    *(float4*)(hw + tid*8)     = make_float4(x[0]*rs*wa.x, x[1]*rs*wa.y, x[2]*rs*wa.z, x[3]*rs*wa.w);
    *(float4*)(hw + tid*8 + 4) = make_float4(x[4]*rs*wb.x, x[5]*rs*wb.y, x[6]*rs*wb.z, x[7]*rs*wb.w);
    __syncthreads();   // also drains group-0 staging

    for(int t=0;t<4;t++){
        if(t){
            __syncthreads();   // group t-1 LDS reads retired before overwrite
            int row = blockIdx.x*16 + t*4 + wid;
            const float* gr = Wg + (size_t)row*H;
            const float* ur = Wu + (size_t)row*H;
#pragma unroll
            for(int i=0;i<8;i++) stage16(gr + i*256 + lane*4, wlds + wid*4096 + i*256);
#pragma unroll
            for(int i=0;i<8;i++) stage16(ur + i*256 + lane*4, wlds + wid*4096 + 2048 + i*256);
            __syncthreads();   // drain
        }
        int row = blockIdx.x*16 + t*4 + wid;
        float ag = 0.f, au = 0.f;
#pragma unroll
        for(int i=0;i<8;i++){
            float4 gv = *(const float4*)(wlds + wid*4096 + i*256 + lane*4);
            float4 uv = *(const float4*)(wlds + wid*4096 + 2048 + i*256 + lane*4);
            float4 hv = *(const float4*)(hw + i*256 + lane*4);
            ag += gv.x*hv.x + gv.y*hv.y + gv.z*hv.z + gv.w*hv.w;
            au += uv.x*hv.x + uv.y*hv.y + uv.z*hv.z + uv.w*hv.w;
        }
        ag = wave_sum(ag);
        au = wave_sum(au);
        if(lane==0){
            float sg = ag/(1.f + __expf(-ag));
            act[row] = sg*au;
        }
    }
}

// ---------- K7: persistent down matvec + residual. grid 512 x 256 ----------
// 2 groups of 2 rows each (4 waves = 2 rows x 2 halves), LDS-staged.
__global__ __launch_bounds__(256,2) void k_down(const float* __restrict__ Wd,
                                                const float* __restrict__ act,
                                                const float* __restrict__ x,
                                                float* __restrict__ out){
    __shared__ __align__(16) float wlds[4*4096];   // 64KB: 16KB half-row per wave
    __shared__ float part[4];
    int tid = threadIdx.x, wid = tid>>6, lane = tid&63;
    int half = wid&1;
    for(int t=0;t<2;t++){
        if(t) __syncthreads();   // prior group LDS reads retired
        int row = blockIdx.x*4 + t*2 + (wid>>1);
        const float* wr = Wd + (size_t)row*IDIM + half*4096;
#pragma unroll
        for(int i=0;i<16;i++) stage16(wr + i*256 + lane*4, wlds + wid*4096 + i*256);
        __syncthreads();   // drain
        float acc = 0.f;
#pragma unroll
        for(int i=0;i<16;i++){
            float4 rv = *(const float4*)(wlds + wid*4096 + i*256 + lane*4);
            float4 av = *(const float4*)(act + half*4096 + i*256 + lane*4);
            acc += rv.x*av.x + rv.y*av.y + rv.z*av.z + rv.w*av.w;
        }
        acc = wave_sum(acc);
        if(lane==0) part[wid] = acc;
        __syncthreads();
        if(tid < 2){
            int rr = blockIdx.x*4 + t*2 + tid;
            out[rr] = x[rr] + part[tid*2] + part[tid*2+1];
        }
    }
}

extern "C" void kernel_launch(void* const* d_in, const int* in_sizes, int n_in,
                              void* d_out, int out_size, void* d_ws, size_t ws_size,
                              hipStream_t stream){
    const float* hs   = (const float*)d_in[0];
    const int*   pos  = (const int*)d_in[1];
    const float* mask = (const float*)d_in[2];
    const float* Wq   = (const float*)d_in[3];
    const float* Wk   = (const float*)d_in[4];
    const float* Wv   = (const float*)d_in[5];
    const float* Wo   = (const float*)d_in[6];
    const float* qn   = (const float*)d_in[7];
    const float* kn   = (const float*)d_in[8];
    const float* ln1  = (const float*)d_in[9];
    const float* ln2  = (const float*)d_in[10];
    const float* Wg   = (const float*)d_in[11];
    const float* Wu   = (const float*)d_in[12];
    const float* Wd   = (const float*)d_in[13];
    const float* cache= (const float*)d_in[14];
    const float* rc   = (const float*)d_in[15];
    const float* rsn  = (const float*)d_in[16];
    float* out = (float*)d_out;

    float* ws       = (float*)d_ws;
    float* qg       = ws;                // 4096
    float* kvec     = ws + 4096;         // 512
    float* vvec     = ws + 4608;         // 512
    float* q_rope   = ws + 5120;         // 2048
    float* gate_sig = ws + 7168;         // 2048
    float* xres     = ws + 9216;         // 2048
    float* attn     = ws + 15360;        // 2048
    float* act      = ws + 17408;        // 8192
    float* knew     = ws + 25600;        // 512
    float* vnew     = ws + 26112;        // 512
    int nchunk = 64;
    while(nchunk > 1){
        size_t need = (size_t)(26624 + 2*NH*nchunk + (size_t)NH*nchunk*128) * 4;
        if(need <= ws_size) break;
        nchunk >>= 1;
    }
    int chunk = CTX / nchunk;
    float* part_m = ws + 26624;
    float* part_l = part_m + NH*nchunk;
    float* part_o = part_l + NH*nchunk;

    k_qkv<<<576,256,0,stream>>>(Wq, Wk, Wv, hs, ln1, qg, kvec, vvec);
    k_rope<<<20,64,0,stream>>>(qg, kvec, vvec, pos, qn, kn, rc, rsn, q_rope, gate_sig, knew, vnew);
    dim3 g3(nchunk, NKV);
    k_attn_part<<<g3,128,0,stream>>>(cache, q_rope, mask, pos, knew, vnew,
                                     part_m, part_l, part_o, nchunk, chunk);
    k_attn_red<<<16,128,0,stream>>>(part_m, part_l, part_o, gate_sig, attn, nchunk);
    k_wo<<<512,256,0,stream>>>(Wo, attn, hs, xres);
    k_gateup<<<512,256,0,stream>>>(Wg, Wu, xres, ln2, act);
    k_down<<<512,256,0,stream>>>(Wd, act, xres, out);
}

// Round 6
// 309.895 us; speedup vs baseline: 1.0512x; 1.0512x over previous
//
#include <hip/hip_runtime.h>

#define H 2048
#define NH 16
#define NKV 4
#define HD 128
#define CTX 8192
#define IDIM 8192
#define EPS 1e-6f
#define SCALE 0.08838834764831845f

__device__ __forceinline__ float wave_sum(float x){
#pragma unroll
    for(int o=32;o>0;o>>=1) x += __shfl_xor(x,o,64);
    return x;
}
__device__ __forceinline__ float wave_max(float x){
#pragma unroll
    for(int o=32;o>0;o>>=1) x = fmaxf(x,__shfl_xor(x,o,64));
    return x;
}
__device__ __forceinline__ void keep4(const float4& v){
    asm volatile("" :: "v"(v.x), "v"(v.y), "v"(v.z), "v"(v.w));
}
// Async global->LDS stage: 16B/lane, fire-and-forget (no dest VGPRs). Dest =
// uniform base + lane*16. Drained by the vmcnt(0) at __syncthreads().
__device__ __forceinline__ void stage16(const float* g, float* l){
    __builtin_amdgcn_global_load_lds(
        (const __attribute__((address_space(1))) void*)g,
        (__attribute__((address_space(3))) void*)l, 16, 0, 0);
}

// ---------- K1: ln1-RMSNorm + QKV matvec. grid 576 x 512 ----------
// 8 waves/block, one 8KB weight row per wave, staged async under the norm.
// 72KB LDS -> 2 blocks/CU = 16 waves/CU resident (duty-cycle fix).
__global__ __launch_bounds__(512) void k_qkv(const float* __restrict__ Wq,
                                             const float* __restrict__ Wk,
                                             const float* __restrict__ Wv,
                                             const float* __restrict__ hs,
                                             const float* __restrict__ ln1,
                                             float* __restrict__ qg,
                                             float* __restrict__ kvec,
                                             float* __restrict__ vvec){
    __shared__ __align__(16) float hw[H];          // 8KB
    __shared__ __align__(16) float wlds[8*2048];   // 64KB: one row per wave
    __shared__ float red[8];
    int tid = threadIdx.x, wid = tid>>6, lane = tid&63;
    int row = blockIdx.x*8 + wid;
    const float* wr; float* op;
    if(row < 4096)      { wr = Wq + (size_t)row*H;        op = qg   + row; }
    else if(row < 4608) { wr = Wk + (size_t)(row-4096)*H; op = kvec + (row-4096); }
    else                { wr = Wv + (size_t)(row-4608)*H; op = vvec + (row-4608); }
    // small vector loads first
    float4 a  = *(const float4*)(hs  + tid*4);
    float4 wa = *(const float4*)(ln1 + tid*4);
    // async-stage the weight row (hidden under the norm phase)
#pragma unroll
    for(int i=0;i<8;i++) stage16(wr + i*256 + lane*4, wlds + wid*2048 + i*256);

    float ss = a.x*a.x + a.y*a.y + a.z*a.z + a.w*a.w;
    ss = wave_sum(ss);
    if(lane==0) red[wid] = ss;
    __syncthreads();   // red visible + stage drained
    float tot = red[0]+red[1]+red[2]+red[3]+red[4]+red[5]+red[6]+red[7];
    float rs = rsqrtf(tot/(float)H + EPS);
    *(float4*)(hw + tid*4) = make_float4(a.x*rs*wa.x, a.y*rs*wa.y, a.z*rs*wa.z, a.w*rs*wa.w);
    __syncthreads();   // hw visible

    float acc = 0.f;
#pragma unroll
    for(int i=0;i<8;i++){
        float4 rv = *(const float4*)(wlds + wid*2048 + i*256 + lane*4);
        float4 hv = *(const float4*)(hw + i*256 + lane*4);
        acc += rv.x*hv.x + rv.y*hv.y + rv.z*hv.z + rv.w*hv.w;
    }
    acc = wave_sum(acc);
    if(lane==0) *op = acc;
}

// ---------- K2: q/k RMS + RoPE + gate sigmoid. grid 20 x 64 ----------
__global__ __launch_bounds__(64) void k_rope(const float* __restrict__ qg,
                                             const float* __restrict__ kvec,
                                             const float* __restrict__ vvec,
                                             const int* __restrict__ pos,
                                             const float* __restrict__ qn,
                                             const float* __restrict__ kn,
                                             const float* __restrict__ rc,
                                             const float* __restrict__ rsn,
                                             float* __restrict__ q_rope,
                                             float* __restrict__ gate_sig,
                                             float* __restrict__ knew,
                                             float* __restrict__ vnew){
    int b = blockIdx.x, lane = threadIdx.x;
    int p = pos[0];
    float c = rc[(size_t)p*64 + lane];
    float s = rsn[(size_t)p*64 + lane];
    if(b < NH){
        int h = b;
        float x1 = qg[h*256 + lane], x2 = qg[h*256 + 64 + lane];
        float ssq = wave_sum(x1*x1 + x2*x2);
        float r = rsqrtf(ssq/128.f + EPS);
        float n1 = x1*r*qn[lane];
        float n2 = x2*r*qn[lane+64];
        q_rope[h*128 + lane]      = n1*c - n2*s;
        q_rope[h*128 + 64 + lane] = n2*c + n1*s;
        float g1 = qg[h*256 + 128 + lane], g2 = qg[h*256 + 192 + lane];
        gate_sig[h*128 + lane]      = 1.f/(1.f + __expf(-g1));
        gate_sig[h*128 + 64 + lane] = 1.f/(1.f + __expf(-g2));
    } else {
        int j = b - NH;
        float x1 = kvec[j*128 + lane], x2 = kvec[j*128 + 64 + lane];
        float ssq = wave_sum(x1*x1 + x2*x2);
        float r = rsqrtf(ssq/128.f + EPS);
        float n1 = x1*r*kn[lane];
        float n2 = x2*r*kn[lane+64];
        knew[j*128 + lane]      = n1*c - n2*s;
        knew[j*128 + 64 + lane] = n2*c + n1*s;
        vnew[j*128 + lane]      = vvec[j*128 + lane];
        vnew[j*128 + 64 + lane] = vvec[j*128 + 64 + lane];
    }
}

// ---------- K3: flash-decode partials. grid (nchunk, NKV) x 128 ----------
// (unchanged)
__global__ __launch_bounds__(128) void k_attn_part(const float* __restrict__ cache,
                                                   const float* __restrict__ q_rope,
                                                   const float* __restrict__ mask,
                                                   const int* __restrict__ pos,
                                                   const float* __restrict__ knew,
                                                   const float* __restrict__ vnew,
                                                   float* __restrict__ part_m,
                                                   float* __restrict__ part_l,
                                                   float* __restrict__ part_o,
                                                   int nchunk, int chunk){
    int j = blockIdx.y, ci = blockIdx.x, tid = threadIdx.x;
    int p = pos[0];
    __shared__ float q_s[512];
    __shared__ float s_s[512];
    __shared__ float m_s[4], l_s[4], mt_s[4], lt_s[4];
#pragma unroll
    for(int t=0;t<4;t++) q_s[t*128 + tid] = q_rope[j*512 + t*128 + tid];
    if(tid < 4){ m_s[tid] = -3.0e38f; l_s[tid] = 0.f; }
    float o0=0.f,o1=0.f,o2=0.f,o3=0.f;
    __syncthreads();
    int base0 = ci*chunk;
    for(int s0=0; s0<chunk; s0+=128){
        int c = base0 + s0 + tid;
        const float* kr = (c==p) ? (knew + (size_t)j*HD)
                                 : (cache + ((size_t)j*CTX + c)*HD);
        float a0=0.f,a1=0.f,a2=0.f,a3=0.f;
        for(int d0=0; d0<HD; d0+=32){
            float4 u8[8];
#pragma unroll
            for(int t=0;t<8;t++) u8[t] = *(const float4*)(kr + d0 + t*4);
#pragma unroll
            for(int t=0;t<8;t++) keep4(u8[t]);
#pragma unroll
            for(int t=0;t<8;t++){
                int dd = d0 + t*4;
                const float* q0=q_s+dd; const float* q1=q_s+128+dd;
                const float* q2=q_s+256+dd; const float* q3=q_s+384+dd;
                a0 += q0[0]*u8[t].x+q0[1]*u8[t].y+q0[2]*u8[t].z+q0[3]*u8[t].w;
                a1 += q1[0]*u8[t].x+q1[1]*u8[t].y+q1[2]*u8[t].z+q1[3]*u8[t].w;
                a2 += q2[0]*u8[t].x+q2[1]*u8[t].y+q2[2]*u8[t].z+q2[3]*u8[t].w;
                a3 += q3[0]*u8[t].x+q3[1]*u8[t].y+q3[2]*u8[t].z+q3[3]*u8[t].w;
            }
        }
        float mv = mask[c];
        s_s[tid]       = a0*SCALE + mv;
        s_s[128 + tid] = a1*SCALE + mv;
        s_s[256 + tid] = a2*SCALE + mv;
        s_s[384 + tid] = a3*SCALE + mv;
        __syncthreads();
        int wid = tid>>6, lane = tid&63;
#pragma unroll
        for(int hh=0; hh<2; hh++){
            int h = wid*2 + hh;
            float v0 = s_s[h*128 + lane], v1 = s_s[h*128 + 64 + lane];
            float m = wave_max(fmaxf(v0, v1));
            float l = wave_sum(__expf(v0 - m) + __expf(v1 - m));
            if(lane==0){ mt_s[h]=m; lt_s[h]=l; }
        }
        __syncthreads();
        float mn[4], sc_old[4];
#pragma unroll
        for(int h=0;h<4;h++){
            mn[h] = fmaxf(m_s[h], mt_s[h]);
            sc_old[h] = __expf(m_s[h] - mn[h]);
        }
        float w0 = __expf(s_s[tid]       - mn[0]);
        float w1 = __expf(s_s[128 + tid] - mn[1]);
        float w2 = __expf(s_s[256 + tid] - mn[2]);
        float w3 = __expf(s_s[384 + tid] - mn[3]);
        __syncthreads();
        s_s[tid]=w0; s_s[128+tid]=w1; s_s[256+tid]=w2; s_s[384+tid]=w3;
        if(tid < 4){
            l_s[tid] = l_s[tid]*sc_old[tid] + lt_s[tid]*__expf(mt_s[tid] - mn[tid]);
            m_s[tid] = mn[tid];
        }
        __syncthreads();
        o0 *= sc_old[0]; o1 *= sc_old[1]; o2 *= sc_old[2]; o3 *= sc_old[3];
        const float* vb = cache + (size_t)NKV*CTX*HD + ((size_t)j*CTX + base0 + s0)*HD;
        for(int cc0=0; cc0<128; cc0+=16){
            float v[16];
#pragma unroll
            for(int t=0;t<16;t++){
                int gpos = base0 + s0 + cc0 + t;   // wave-uniform select
                const float* vrow = (gpos==p) ? (vnew + (size_t)j*HD)
                                              : (vb + (size_t)(cc0+t)*HD);
                v[t] = vrow[tid];
            }
            asm volatile("" :: "v"(v[0]),  "v"(v[1]),  "v"(v[2]),  "v"(v[3]),
                              "v"(v[4]),  "v"(v[5]),  "v"(v[6]),  "v"(v[7]),
                              "v"(v[8]),  "v"(v[9]),  "v"(v[10]), "v"(v[11]),
                              "v"(v[12]), "v"(v[13]), "v"(v[14]), "v"(v[15]));
#pragma unroll
            for(int t=0;t<16;t++){
                int cc = cc0 + t;
                o0 += s_s[cc]*v[t];
                o1 += s_s[128+cc]*v[t];
                o2 += s_s[256+cc]*v[t];
                o3 += s_s[384+cc]*v[t];
            }
        }
        __syncthreads();
    }
    int h0 = j*4;
    part_o[((size_t)(h0+0)*nchunk + ci)*128 + tid] = o0;
    part_o[((size_t)(h0+1)*nchunk + ci)*128 + tid] = o1;
    part_o[((size_t)(h0+2)*nchunk + ci)*128 + tid] = o2;
    part_o[((size_t)(h0+3)*nchunk + ci)*128 + tid] = o3;
    if(tid < 4){
        part_m[(h0+tid)*nchunk + ci] = m_s[tid];
        part_l[(h0+tid)*nchunk + ci] = l_s[tid];
    }
}

// ---------- K4: combine chunks + gate. grid 16 x 128 ----------
// Lane-parallel m/l reduction (was 2 chains of 64 serial dependent loads);
// e[i] broadcast via LDS so the o-loop loads are independent and pipeline.
__global__ __launch_bounds__(128) void k_attn_red(const float* __restrict__ part_m,
                                                  const float* __restrict__ part_l,
                                                  const float* __restrict__ part_o,
                                                  const float* __restrict__ gate_sig,
                                                  float* __restrict__ attn,
                                                  int nchunk){
    __shared__ float e_s[64];
    __shared__ float lg_s;
    int h = blockIdx.x, tid = threadIdx.x, lane = tid&63, w = tid>>6;
    if(w == 0){
        float pm = (lane < nchunk) ? part_m[h*nchunk + lane] : -3.0e38f;
        float pl = (lane < nchunk) ? part_l[h*nchunk + lane] : 0.f;
        float mg = wave_max(pm);
        float e  = (lane < nchunk) ? __expf(pm - mg) : 0.f;
        float lg = wave_sum(pl * e);
        if(lane < 64) e_s[lane] = e;
        if(lane == 0) lg_s = lg;
    }
    __syncthreads();
    float lg = lg_s;
    float oa = 0.f;
    for(int i=0;i<nchunk;i++)
        oa += e_s[i]*part_o[((size_t)h*nchunk + i)*128 + tid];
    attn[h*128 + tid] = oa/lg * gate_sig[h*128 + tid];
}

// ---------- K5: Wo matvec + residual, LDS-staged. grid 256 x 512 ----------
__global__ __launch_bounds__(512) void k_wo(const float* __restrict__ Wo,
                                            const float* __restrict__ attn,
                                            const float* __restrict__ resid,
                                            float* __restrict__ x){
    __shared__ __align__(16) float wlds[8*2048];   // 64KB: one row per wave
    int tid = threadIdx.x, wid = tid>>6, lane = tid&63;
    int row = blockIdx.x*8 + wid;
    const float* wr = Wo + (size_t)row*H;
    // activation loads first (register-resident, small)
    float4 hv[8];
#pragma unroll
    for(int i=0;i<8;i++) hv[i] = *(const float4*)(attn + i*256 + lane*4);
    // async-stage the weight row
#pragma unroll
    for(int i=0;i<8;i++) stage16(wr + i*256 + lane*4, wlds + wid*2048 + i*256);
    __syncthreads();
    float acc = 0.f;
#pragma unroll
    for(int i=0;i<8;i++){
        float4 rv = *(const float4*)(wlds + wid*2048 + i*256 + lane*4);
        acc += rv.x*hv[i].x + rv.y*hv[i].y + rv.z*hv[i].z + rv.w*hv[i].w;
    }
    acc = wave_sum(acc);
    if(lane==0) x[row] = resid[row] + acc;
}

// ---------- K6: ln2-RMSNorm + gate/up matvec + SiLU. grid 1024 x 512 ----------
// 8 waves/block, one output row per wave, TWO passes (g then u) reusing one
// 64KB buffer: 72KB LDS -> 2 blocks/CU = 16 waves/CU (vs 8 in round 4).
// Pass-1 stage hidden under the norm; pass-2 stage covered by the co-resident
// block's compute.
__global__ __launch_bounds__(512) void k_gateup(const float* __restrict__ Wg,
                                                const float* __restrict__ Wu,
                                                const float* __restrict__ xres,
                                                const float* __restrict__ ln2,
                                                float* __restrict__ act){
    __shared__ __align__(16) float hw[H];          // 8KB
    __shared__ __align__(16) float wlds[8*2048];   // 64KB: one row per wave
    __shared__ float red[8];
    int tid = threadIdx.x, wid = tid>>6, lane = tid&63;
    int row = blockIdx.x*8 + wid;
    const float* gr = Wg + (size_t)row*H;
    const float* ur = Wu + (size_t)row*H;
    // small vector loads first
    float4 a  = *(const float4*)(xres + (size_t)tid*4);
    float4 wa = *(const float4*)(ln2  + (size_t)tid*4);
    // stage the gate row (hidden under the norm phase)
#pragma unroll
    for(int i=0;i<8;i++) stage16(gr + i*256 + lane*4, wlds + wid*2048 + i*256);

    float ss = a.x*a.x + a.y*a.y + a.z*a.z + a.w*a.w;
    ss = wave_sum(ss);
    if(lane==0) red[wid] = ss;
    __syncthreads();   // red visible + g-stage drained
    float tot = red[0]+red[1]+red[2]+red[3]+red[4]+red[5]+red[6]+red[7];
    float rs = rsqrtf(tot/(float)H + EPS);
    *(float4*)(hw + tid*4) = make_float4(a.x*rs*wa.x, a.y*rs*wa.y, a.z*rs*wa.z, a.w*rs*wa.w);
    __syncthreads();   // hw visible

    float ag = 0.f;
#pragma unroll
    for(int i=0;i<8;i++){
        float4 gv = *(const float4*)(wlds + wid*2048 + i*256 + lane*4);
        float4 hv = *(const float4*)(hw + i*256 + lane*4);
        ag += gv.x*hv.x + gv.y*hv.y + gv.z*hv.z + gv.w*hv.w;
    }
    ag = wave_sum(ag);
    __syncthreads();   // all g reads retired before overwrite
    // stage the up row into the same buffer
#pragma unroll
    for(int i=0;i<8;i++) stage16(ur + i*256 + lane*4, wlds + wid*2048 + i*256);
    __syncthreads();   // u-stage drained

    float au = 0.f;
#pragma unroll
    for(int i=0;i<8;i++){
        float4 uv = *(const float4*)(wlds + wid*2048 + i*256 + lane*4);
        float4 hv = *(const float4*)(hw + i*256 + lane*4);
        au += uv.x*hv.x + uv.y*hv.y + uv.z*hv.z + uv.w*hv.w;
    }
    au = wave_sum(au);
    if(lane==0){
        float sg = ag/(1.f + __expf(-ag));
        act[row] = sg*au;
    }
}

// ---------- K7: down matvec + residual, LDS-staged, 2 waves/row. grid 1024 x 256 ----------
// (round-4 form: transient, cross-block pipelined)
__global__ __launch_bounds__(256,2) void k_down(const float* __restrict__ Wd,
                                                const float* __restrict__ act,
                                                const float* __restrict__ x,
                                                float* __restrict__ out){
    __shared__ __align__(16) float wlds[4*4096];   // 64KB: 16KB half-row per wave
    __shared__ float part[4];
    int tid = threadIdx.x, wid = tid>>6, lane = tid&63;
    int row  = blockIdx.x*2 + (wid>>1);
    int half = wid&1;
    const float* wr = Wd + (size_t)row*IDIM + half*4096;
#pragma unroll
    for(int i=0;i<16;i++) stage16(wr + i*256 + lane*4, wlds + wid*4096 + i*256);
    __syncthreads();
    float acc = 0.f;
#pragma unroll
    for(int i=0;i<16;i++){
        float4 rv = *(const float4*)(wlds + wid*4096 + i*256 + lane*4);
        float4 av = *(const float4*)(act + half*4096 + i*256 + lane*4);
        acc += rv.x*av.x + rv.y*av.y + rv.z*av.z + rv.w*av.w;
    }
    acc = wave_sum(acc);
    if(lane==0) part[wid] = acc;
    __syncthreads();
    if(tid < 2){
        int rr = blockIdx.x*2 + tid;
        out[rr] = x[rr] + part[tid*2] + part[tid*2+1];
    }
}

extern "C" void kernel_launch(void* const* d_in, const int* in_sizes, int n_in,
                              void* d_out, int out_size, void* d_ws, size_t ws_size,
                              hipStream_t stream){
    const float* hs   = (const float*)d_in[0];
    const int*   pos  = (const int*)d_in[1];
    const float* mask = (const float*)d_in[2];
    const float* Wq   = (const float*)d_in[3];
    const float* Wk   = (const float*)d_in[4];
    const float* Wv   = (const float*)d_in[5];
    const float* Wo   = (const float*)d_in[6];
    const float* qn   = (const float*)d_in[7];
    const float* kn   = (const float*)d_in[8];
    const float* ln1  = (const float*)d_in[9];
    const float* ln2  = (const float*)d_in[10];
    const float* Wg   = (const float*)d_in[11];
    const float* Wu   = (const float*)d_in[12];
    const float* Wd   = (const float*)d_in[13];
    const float* cache= (const float*)d_in[14];
    const float* rc   = (const float*)d_in[15];
    const float* rsn  = (const float*)d_in[16];
    float* out = (float*)d_out;

    float* ws       = (float*)d_ws;
    float* qg       = ws;                // 4096
    float* kvec     = ws + 4096;         // 512
    float* vvec     = ws + 4608;         // 512
    float* q_rope   = ws + 5120;         // 2048
    float* gate_sig = ws + 7168;         // 2048
    float* xres     = ws + 9216;         // 2048
    float* attn     = ws + 15360;        // 2048
    float* act      = ws + 17408;        // 8192
    float* knew     = ws + 25600;        // 512
    float* vnew     = ws + 26112;        // 512
    int nchunk = 64;
    while(nchunk > 1){
        size_t need = (size_t)(26624 + 2*NH*nchunk + (size_t)NH*nchunk*128) * 4;
        if(need <= ws_size) break;
        nchunk >>= 1;
    }
    int chunk = CTX / nchunk;
    float* part_m = ws + 26624;
    float* part_l = part_m + NH*nchunk;
    float* part_o = part_l + NH*nchunk;

    k_qkv<<<576,512,0,stream>>>(Wq, Wk, Wv, hs, ln1, qg, kvec, vvec);
    k_rope<<<20,64,0,stream>>>(qg, kvec, vvec, pos, qn, kn, rc, rsn, q_rope, gate_sig, knew, vnew);
    dim3 g3(nchunk, NKV);
    k_attn_part<<<g3,128,0,stream>>>(cache, q_rope, mask, pos, knew, vnew,
                                     part_m, part_l, part_o, nchunk, chunk);
    k_attn_red<<<16,128,0,stream>>>(part_m, part_l, part_o, gate_sig, attn, nchunk);
    k_wo<<<256,512,0,stream>>>(Wo, attn, hs, xres);
    k_gateup<<<1024,512,0,stream>>>(Wg, Wu, xres, ln2, act);
    k_down<<<1024,256,0,stream>>>(Wd, act, xres, out);
}

// Round 7
// 305.780 us; speedup vs baseline: 1.0653x; 1.0135x over previous
//
#include <hip/hip_runtime.h>

#define H 2048
#define NH 16
#define NKV 4
#define HD 128
#define CTX 8192
#define IDIM 8192
#define EPS 1e-6f
#define SCALE 0.08838834764831845f

__device__ __forceinline__ float wave_sum(float x){
#pragma unroll
    for(int o=32;o>0;o>>=1) x += __shfl_xor(x,o,64);
    return x;
}
__device__ __forceinline__ float wave_max(float x){
#pragma unroll
    for(int o=32;o>0;o>>=1) x = fmaxf(x,__shfl_xor(x,o,64));
    return x;
}
__device__ __forceinline__ void keep4(const float4& v){
    asm volatile("" :: "v"(v.x), "v"(v.y), "v"(v.z), "v"(v.w));
}
// Async global->LDS stage: 16B/lane, fire-and-forget (no dest VGPRs). Dest =
// uniform base + lane*16. Drained by the vmcnt(0) at __syncthreads().
__device__ __forceinline__ void stage16(const float* g, float* l){
    __builtin_amdgcn_global_load_lds(
        (const __attribute__((address_space(1))) void*)g,
        (__attribute__((address_space(3))) void*)l, 16, 0, 0);
}

// ---------- K1: ln1-RMSNorm + QKV matvec. grid 576 x 512 ----------
__global__ __launch_bounds__(512) void k_qkv(const float* __restrict__ Wq,
                                             const float* __restrict__ Wk,
                                             const float* __restrict__ Wv,
                                             const float* __restrict__ hs,
                                             const float* __restrict__ ln1,
                                             float* __restrict__ qg,
                                             float* __restrict__ kvec,
                                             float* __restrict__ vvec){
    __shared__ __align__(16) float hw[H];          // 8KB
    __shared__ __align__(16) float wlds[8*2048];   // 64KB: one row per wave
    __shared__ float red[8];
    int tid = threadIdx.x, wid = tid>>6, lane = tid&63;
    int row = blockIdx.x*8 + wid;
    const float* wr; float* op;
    if(row < 4096)      { wr = Wq + (size_t)row*H;        op = qg   + row; }
    else if(row < 4608) { wr = Wk + (size_t)(row-4096)*H; op = kvec + (row-4096); }
    else                { wr = Wv + (size_t)(row-4608)*H; op = vvec + (row-4608); }
    float4 a  = *(const float4*)(hs  + tid*4);
    float4 wa = *(const float4*)(ln1 + tid*4);
#pragma unroll
    for(int i=0;i<8;i++) stage16(wr + i*256 + lane*4, wlds + wid*2048 + i*256);

    float ss = a.x*a.x + a.y*a.y + a.z*a.z + a.w*a.w;
    ss = wave_sum(ss);
    if(lane==0) red[wid] = ss;
    __syncthreads();
    float tot = red[0]+red[1]+red[2]+red[3]+red[4]+red[5]+red[6]+red[7];
    float rs = rsqrtf(tot/(float)H + EPS);
    *(float4*)(hw + tid*4) = make_float4(a.x*rs*wa.x, a.y*rs*wa.y, a.z*rs*wa.z, a.w*rs*wa.w);
    __syncthreads();

    float acc = 0.f;
#pragma unroll
    for(int i=0;i<8;i++){
        float4 rv = *(const float4*)(wlds + wid*2048 + i*256 + lane*4);
        float4 hv = *(const float4*)(hw + i*256 + lane*4);
        acc += rv.x*hv.x + rv.y*hv.y + rv.z*hv.z + rv.w*hv.w;
    }
    acc = wave_sum(acc);
    if(lane==0) *op = acc;
}

// ---------- K2: q/k RMS + RoPE + gate sigmoid. grid 20 x 64 ----------
__global__ __launch_bounds__(64) void k_rope(const float* __restrict__ qg,
                                             const float* __restrict__ kvec,
                                             const float* __restrict__ vvec,
                                             const int* __restrict__ pos,
                                             const float* __restrict__ qn,
                                             const float* __restrict__ kn,
                                             const float* __restrict__ rc,
                                             const float* __restrict__ rsn,
                                             float* __restrict__ q_rope,
                                             float* __restrict__ gate_sig,
                                             float* __restrict__ knew,
                                             float* __restrict__ vnew){
    int b = blockIdx.x, lane = threadIdx.x;
    int p = pos[0];
    float c = rc[(size_t)p*64 + lane];
    float s = rsn[(size_t)p*64 + lane];
    if(b < NH){
        int h = b;
        float x1 = qg[h*256 + lane], x2 = qg[h*256 + 64 + lane];
        float ssq = wave_sum(x1*x1 + x2*x2);
        float r = rsqrtf(ssq/128.f + EPS);
        float n1 = x1*r*qn[lane];
        float n2 = x2*r*qn[lane+64];
        q_rope[h*128 + lane]      = n1*c - n2*s;
        q_rope[h*128 + 64 + lane] = n2*c + n1*s;
        float g1 = qg[h*256 + 128 + lane], g2 = qg[h*256 + 192 + lane];
        gate_sig[h*128 + lane]      = 1.f/(1.f + __expf(-g1));
        gate_sig[h*128 + 64 + lane] = 1.f/(1.f + __expf(-g2));
    } else {
        int j = b - NH;
        float x1 = kvec[j*128 + lane], x2 = kvec[j*128 + 64 + lane];
        float ssq = wave_sum(x1*x1 + x2*x2);
        float r = rsqrtf(ssq/128.f + EPS);
        float n1 = x1*r*kn[lane];
        float n2 = x2*r*kn[lane+64];
        knew[j*128 + lane]      = n1*c - n2*s;
        knew[j*128 + 64 + lane] = n2*c + n1*s;
        vnew[j*128 + lane]      = vvec[j*128 + lane];
        vnew[j*128 + 64 + lane] = vvec[j*128 + 64 + lane];
    }
}

// ---------- K3: flash-decode partials v2. grid (nchunk, NKV) x 256 ----------
// Producer/consumer in-block: waves 2-3 async-stage the 64KB V-tile into LDS
// while waves 0-1 compute the K-dots -> V latency hides under K compute.
// 4-wave softmax (one head per wave); PV reads V from LDS with row-halves
// split across wave pairs (2x PV parallelism), halves reduced at the end.
__global__ __launch_bounds__(256) void k_attn_part(const float* __restrict__ cache,
                                                   const float* __restrict__ q_rope,
                                                   const float* __restrict__ mask,
                                                   const int* __restrict__ pos,
                                                   const float* __restrict__ knew,
                                                   const float* __restrict__ vnew,
                                                   float* __restrict__ part_m,
                                                   float* __restrict__ part_l,
                                                   float* __restrict__ part_o,
                                                   int nchunk, int chunk){
    int j = blockIdx.y, ci = blockIdx.x, tid = threadIdx.x;
    int p = pos[0];
    __shared__ __align__(16) float q_s[512];
    __shared__ float s_s[512];                 // scores -> weights
    __shared__ __align__(16) float V_s[128*128];   // 64KB V tile
    __shared__ float m_s[4], l_s[4], sc_s[4];
    int lane = tid&63, w = tid>>6;
    int base0 = ci*chunk;

    q_s[tid]       = q_rope[j*512 + tid];
    q_s[256 + tid] = q_rope[j*512 + 256 + tid];
    if(tid < 4){ m_s[tid] = -3.0e38f; l_s[tid] = 0.f; }
    float o0=0.f,o1=0.f,o2=0.f,o3=0.f;
    __syncthreads();   // q_s / init visible; no stages issued yet

    for(int s0=0; s0<chunk; s0+=128){
        // waves 2-3: stage this tile's V (64KB) async; arrival hidden under K
        if(w >= 2){
            const float* vb = cache + (size_t)NKV*CTX*HD + ((size_t)j*CTX + base0 + s0)*HD;
            int half = w - 2;
#pragma unroll
            for(int i=0;i<32;i++){
                int idx = half*32 + i;
                stage16(vb + idx*256 + lane*4, V_s + idx*256);
            }
        } else {
            // waves 0-1: K-dot for row c against all 4 heads
            int c = base0 + s0 + tid;   // tid < 128 here
            const float* kr = (c==p) ? (knew + (size_t)j*HD)
                                     : (cache + ((size_t)j*CTX + c)*HD);
            float a0=0.f,a1=0.f,a2=0.f,a3=0.f;
            for(int d0=0; d0<HD; d0+=32){
                float4 u8[8];
#pragma unroll
                for(int t=0;t<8;t++) u8[t] = *(const float4*)(kr + d0 + t*4);
#pragma unroll
                for(int t=0;t<8;t++) keep4(u8[t]);
#pragma unroll
                for(int t=0;t<8;t++){
                    int dd = d0 + t*4;
                    const float* q0=q_s+dd; const float* q1=q_s+128+dd;
                    const float* q2=q_s+256+dd; const float* q3=q_s+384+dd;
                    a0 += q0[0]*u8[t].x+q0[1]*u8[t].y+q0[2]*u8[t].z+q0[3]*u8[t].w;
                    a1 += q1[0]*u8[t].x+q1[1]*u8[t].y+q1[2]*u8[t].z+q1[3]*u8[t].w;
                    a2 += q2[0]*u8[t].x+q2[1]*u8[t].y+q2[2]*u8[t].z+q2[3]*u8[t].w;
                    a3 += q3[0]*u8[t].x+q3[1]*u8[t].y+q3[2]*u8[t].z+q3[3]*u8[t].w;
                }
            }
            float mv = mask[c];
            s_s[tid]       = a0*SCALE + mv;
            s_s[128 + tid] = a1*SCALE + mv;
            s_s[256 + tid] = a2*SCALE + mv;
            s_s[384 + tid] = a3*SCALE + mv;
        }
        __syncthreads();   // V staged + scores visible

        // V p-row fix: replace the cached row at position p with vnew
        int prow = p - (base0 + s0);
        if(prow >= 0 && prow < 128 && tid < 128)
            V_s[prow*128 + tid] = vnew[(size_t)j*HD + tid];

        // softmax: wave w owns head w (all 4 waves busy)
        {
            float v0 = s_s[w*128 + lane], v1 = s_s[w*128 + 64 + lane];
            float mt = wave_max(fmaxf(v0, v1));
            float mn = fmaxf(m_s[w], mt);
            float sc = __expf(m_s[w] - mn);
            float w0 = __expf(v0 - mn), w1 = __expf(v1 - mn);
            float lt = wave_sum(w0 + w1);
            s_s[w*128 + lane]      = w0;
            s_s[w*128 + 64 + lane] = w1;
            if(lane==0){ l_s[w] = l_s[w]*sc + lt; m_s[w] = mn; sc_s[w] = sc; }
        }
        __syncthreads();   // weights + V fix + sc_s visible

        o0 *= sc_s[0]; o1 *= sc_s[1]; o2 *= sc_s[2]; o3 *= sc_s[3];
        // PV: thread handles d = tid&127, row-half rh = tid>>7
        int d = tid & 127, rh = tid >> 7;
        const float* vbase = V_s + rh*64*128 + d;
        const float* p0 = s_s + rh*64;
#pragma unroll 8
        for(int cc=0; cc<64; cc++){
            float v = vbase[cc*128];
            o0 += p0[cc]*v;
            o1 += p0[128+cc]*v;
            o2 += p0[256+cc]*v;
            o3 += p0[384+cc]*v;
        }
        __syncthreads();   // PV reads done before next-iter V overwrite
    }

    // reduce the two row-halves via LDS (V_s is free now)
    int d = tid & 127, rh = tid >> 7;
    V_s[rh*512 + 0*128 + d] = o0;
    V_s[rh*512 + 1*128 + d] = o1;
    V_s[rh*512 + 2*128 + d] = o2;
    V_s[rh*512 + 3*128 + d] = o3;
    __syncthreads();
    if(tid < 128){
#pragma unroll
        for(int h=0;h<4;h++){
            float o = V_s[h*128 + tid] + V_s[512 + h*128 + tid];
            part_o[((size_t)(j*4+h)*nchunk + ci)*128 + tid] = o;
        }
    }
    if(tid < 4){
        part_m[(j*4+tid)*nchunk + ci] = m_s[tid];
        part_l[(j*4+tid)*nchunk + ci] = l_s[tid];
    }
}

// ---------- K4: combine chunks + gate. grid 16 x 128 ----------
__global__ __launch_bounds__(128) void k_attn_red(const float* __restrict__ part_m,
                                                  const float* __restrict__ part_l,
                                                  const float* __restrict__ part_o,
                                                  const float* __restrict__ gate_sig,
                                                  float* __restrict__ attn,
                                                  int nchunk){
    __shared__ float e_s[64];
    __shared__ float lg_s;
    int h = blockIdx.x, tid = threadIdx.x, lane = tid&63, w = tid>>6;
    if(w == 0){
        float pm = (lane < nchunk) ? part_m[h*nchunk + lane] : -3.0e38f;
        float pl = (lane < nchunk) ? part_l[h*nchunk + lane] : 0.f;
        float mg = wave_max(pm);
        float e  = (lane < nchunk) ? __expf(pm - mg) : 0.f;
        float lg = wave_sum(pl * e);
        if(lane < 64) e_s[lane] = e;
        if(lane == 0) lg_s = lg;
    }
    __syncthreads();
    float lg = lg_s;
    float oa = 0.f;
    for(int i=0;i<nchunk;i++)
        oa += e_s[i]*part_o[((size_t)h*nchunk + i)*128 + tid];
    attn[h*128 + tid] = oa/lg * gate_sig[h*128 + tid];
}

// ---------- K5: Wo matvec + residual, LDS-staged. grid 256 x 512 ----------
__global__ __launch_bounds__(512) void k_wo(const float* __restrict__ Wo,
                                            const float* __restrict__ attn,
                                            const float* __restrict__ resid,
                                            float* __restrict__ x){
    __shared__ __align__(16) float wlds[8*2048];   // 64KB: one row per wave
    int tid = threadIdx.x, wid = tid>>6, lane = tid&63;
    int row = blockIdx.x*8 + wid;
    const float* wr = Wo + (size_t)row*H;
    float4 hv[8];
#pragma unroll
    for(int i=0;i<8;i++) hv[i] = *(const float4*)(attn + i*256 + lane*4);
#pragma unroll
    for(int i=0;i<8;i++) stage16(wr + i*256 + lane*4, wlds + wid*2048 + i*256);
    __syncthreads();
    float acc = 0.f;
#pragma unroll
    for(int i=0;i<8;i++){
        float4 rv = *(const float4*)(wlds + wid*2048 + i*256 + lane*4);
        acc += rv.x*hv[i].x + rv.y*hv[i].y + rv.z*hv[i].z + rv.w*hv[i].w;
    }
    acc = wave_sum(acc);
    if(lane==0) x[row] = resid[row] + acc;
}

// ---------- K6: fused ln2-RMSNorm + gate/up matvec + SiLU. grid 2048 x 256 ----------
// REVERTED to the round-4 form (best measured: 48.6us = ~2.8 TB/s read, at the
// structural read-path ceiling). Do not touch further.
__global__ __launch_bounds__(256,2) void k_gateup(const float* __restrict__ Wg,
                                                  const float* __restrict__ Wu,
                                                  const float* __restrict__ xres,
                                                  const float* __restrict__ ln2,
                                                  float* __restrict__ act){
    __shared__ __align__(16) float hw[H];
    __shared__ __align__(16) float wlds[4*4096];   // 64KB: g-row + u-row per wave
    __shared__ float red[4];
    int tid = threadIdx.x, wid = tid>>6, lane = tid&63;
    int row = blockIdx.x*4 + wid;
    const float* gr = Wg + (size_t)row*H;
    const float* ur = Wu + (size_t)row*H;
    float4 a = *(const float4*)(xres + (size_t)tid*8);
    float4 b = *(const float4*)(xres + (size_t)tid*8 + 4);
    float4 wa = *(const float4*)(ln2 + (size_t)tid*8);
    float4 wb = *(const float4*)(ln2 + (size_t)tid*8 + 4);
#pragma unroll
    for(int i=0;i<8;i++) stage16(gr + i*256 + lane*4, wlds + wid*4096 + i*256);
#pragma unroll
    for(int i=0;i<8;i++) stage16(ur + i*256 + lane*4, wlds + wid*4096 + 2048 + i*256);

    float x[8] = {a.x,a.y,a.z,a.w,b.x,b.y,b.z,b.w};
    float ss = 0.f;
#pragma unroll
    for(int i=0;i<8;i++) ss += x[i]*x[i];
    ss = wave_sum(ss);
    if(lane==0) red[wid] = ss;
    __syncthreads();
    float tot = red[0]+red[1]+red[2]+red[3];
    float rs = rsqrtf(tot/(float)H + EPS);
    *(float4*)(hw + tid*8)     = make_float4(x[0]*rs*wa.x, x[1]*rs*wa.y, x[2]*rs*wa.z, x[3]*rs*wa.w);
    *(float4*)(hw + tid*8 + 4) = make_float4(x[4]*rs*wb.x, x[5]*rs*wb.y, x[6]*rs*wb.z, x[7]*rs*wb.w);
    __syncthreads();

    float ag = 0.f, au = 0.f;
#pragma unroll
    for(int i=0;i<8;i++){
        float4 gv = *(const float4*)(wlds + wid*4096 + i*256 + lane*4);
        float4 uv = *(const float4*)(wlds + wid*4096 + 2048 + i*256 + lane*4);
        float4 hv = *(const float4*)(hw + i*256 + lane*4);
        ag += gv.x*hv.x + gv.y*hv.y + gv.z*hv.z + gv.w*hv.w;
        au += uv.x*hv.x + uv.y*hv.y + uv.z*hv.z + uv.w*hv.w;
    }
    ag = wave_sum(ag);
    au = wave_sum(au);
    if(lane==0){
        float sg = ag/(1.f + __expf(-ag));
        act[row] = sg*au;
    }
}

// ---------- K7: down matvec + residual, LDS-staged, 2 waves/row. grid 1024 x 256 ----------
__global__ __launch_bounds__(256,2) void k_down(const float* __restrict__ Wd,
                                                const float* __restrict__ act,
                                                const float* __restrict__ x,
                                                float* __restrict__ out){
    __shared__ __align__(16) float wlds[4*4096];   // 64KB: 16KB half-row per wave
    __shared__ float part[4];
    int tid = threadIdx.x, wid = tid>>6, lane = tid&63;
    int row  = blockIdx.x*2 + (wid>>1);
    int half = wid&1;
    const float* wr = Wd + (size_t)row*IDIM + half*4096;
#pragma unroll
    for(int i=0;i<16;i++) stage16(wr + i*256 + lane*4, wlds + wid*4096 + i*256);
    __syncthreads();
    float acc = 0.f;
#pragma unroll
    for(int i=0;i<16;i++){
        float4 rv = *(const float4*)(wlds + wid*4096 + i*256 + lane*4);
        float4 av = *(const float4*)(act + half*4096 + i*256 + lane*4);
        acc += rv.x*av.x + rv.y*av.y + rv.z*av.z + rv.w*av.w;
    }
    acc = wave_sum(acc);
    if(lane==0) part[wid] = acc;
    __syncthreads();
    if(tid < 2){
        int rr = blockIdx.x*2 + tid;
        out[rr] = x[rr] + part[tid*2] + part[tid*2+1];
    }
}

extern "C" void kernel_launch(void* const* d_in, const int* in_sizes, int n_in,
                              void* d_out, int out_size, void* d_ws, size_t ws_size,
                              hipStream_t stream){
    const float* hs   = (const float*)d_in[0];
    const int*   pos  = (const int*)d_in[1];
    const float* mask = (const float*)d_in[2];
    const float* Wq   = (const float*)d_in[3];
    const float* Wk   = (const float*)d_in[4];
    const float* Wv   = (const float*)d_in[5];
    const float* Wo   = (const float*)d_in[6];
    const float* qn   = (const float*)d_in[7];
    const float* kn   = (const float*)d_in[8];
    const float* ln1  = (const float*)d_in[9];
    const float* ln2  = (const float*)d_in[10];
    const float* Wg   = (const float*)d_in[11];
    const float* Wu   = (const float*)d_in[12];
    const float* Wd   = (const float*)d_in[13];
    const float* cache= (const float*)d_in[14];
    const float* rc   = (const float*)d_in[15];
    const float* rsn  = (const float*)d_in[16];
    float* out = (float*)d_out;

    float* ws       = (float*)d_ws;
    float* qg       = ws;                // 4096
    float* kvec     = ws + 4096;         // 512
    float* vvec     = ws + 4608;         // 512
    float* q_rope   = ws + 5120;         // 2048
    float* gate_sig = ws + 7168;         // 2048
    float* xres     = ws + 9216;         // 2048
    float* attn     = ws + 15360;        // 2048
    float* act      = ws + 17408;        // 8192
    float* knew     = ws + 25600;        // 512
    float* vnew     = ws + 26112;        // 512
    int nchunk = 64;
    while(nchunk > 1){
        size_t need = (size_t)(26624 + 2*NH*nchunk + (size_t)NH*nchunk*128) * 4;
        if(need <= ws_size) break;
        nchunk >>= 1;
    }
    int chunk = CTX / nchunk;
    float* part_m = ws + 26624;
    float* part_l = part_m + NH*nchunk;
    float* part_o = part_l + NH*nchunk;

    k_qkv<<<576,512,0,stream>>>(Wq, Wk, Wv, hs, ln1, qg, kvec, vvec);
    k_rope<<<20,64,0,stream>>>(qg, kvec, vvec, pos, qn, kn, rc, rsn, q_rope, gate_sig, knew, vnew);
    dim3 g3(nchunk, NKV);
    k_attn_part<<<g3,256,0,stream>>>(cache, q_rope, mask, pos, knew, vnew,
                                     part_m, part_l, part_o, nchunk, chunk);
    k_attn_red<<<16,128,0,stream>>>(part_m, part_l, part_o, gate_sig, attn, nchunk);
    k_wo<<<256,512,0,stream>>>(Wo, attn, hs, xres);
    k_gateup<<<2048,256,0,stream>>>(Wg, Wu, xres, ln2, act);
    k_down<<<1024,256,0,stream>>>(Wd, act, xres, out);
}

// Round 8
// 305.695 us; speedup vs baseline: 1.0656x; 1.0003x over previous
//
#include <hip/hip_runtime.h>

#define H 2048
#define NH 16
#define NKV 4
#define HD 128
#define CTX 8192
#define IDIM 8192
#define EPS 1e-6f
#define SCALE 0.08838834764831845f

__device__ __forceinline__ float wave_sum(float x){
#pragma unroll
    for(int o=32;o>0;o>>=1) x += __shfl_xor(x,o,64);
    return x;
}
__device__ __forceinline__ float wave_max(float x){
#pragma unroll
    for(int o=32;o>0;o>>=1) x = fmaxf(x,__shfl_xor(x,o,64));
    return x;
}
__device__ __forceinline__ void keep4(const float4& v){
    asm volatile("" :: "v"(v.x), "v"(v.y), "v"(v.z), "v"(v.w));
}
// Async global->LDS stage: 16B/lane, fire-and-forget (no dest VGPRs). Dest =
// uniform base + lane*16.
__device__ __forceinline__ void stage16(const float* g, float* l){
    __builtin_amdgcn_global_load_lds(
        (const __attribute__((address_space(1))) void*)g,
        (__attribute__((address_space(3))) void*)l, 16, 0, 0);
}
// Counted vmem wait (T4): never drain to 0 in a consume loop. The "memory"
// clobber fences the following ds_reads from hoisting above the wait.
#define WV(N) asm volatile("s_waitcnt vmcnt(" #N ")" ::: "memory")

// ---------- K1: ln1-RMSNorm + QKV matvec. grid 576 x 512 ---------- (unchanged)
__global__ __launch_bounds__(512) void k_qkv(const float* __restrict__ Wq,
                                             const float* __restrict__ Wk,
                                             const float* __restrict__ Wv,
                                             const float* __restrict__ hs,
                                             const float* __restrict__ ln1,
                                             float* __restrict__ qg,
                                             float* __restrict__ kvec,
                                             float* __restrict__ vvec){
    __shared__ __align__(16) float hw[H];          // 8KB
    __shared__ __align__(16) float wlds[8*2048];   // 64KB: one row per wave
    __shared__ float red[8];
    int tid = threadIdx.x, wid = tid>>6, lane = tid&63;
    int row = blockIdx.x*8 + wid;
    const float* wr; float* op;
    if(row < 4096)      { wr = Wq + (size_t)row*H;        op = qg   + row; }
    else if(row < 4608) { wr = Wk + (size_t)(row-4096)*H; op = kvec + (row-4096); }
    else                { wr = Wv + (size_t)(row-4608)*H; op = vvec + (row-4608); }
    float4 a  = *(const float4*)(hs  + tid*4);
    float4 wa = *(const float4*)(ln1 + tid*4);
#pragma unroll
    for(int i=0;i<8;i++) stage16(wr + i*256 + lane*4, wlds + wid*2048 + i*256);

    float ss = a.x*a.x + a.y*a.y + a.z*a.z + a.w*a.w;
    ss = wave_sum(ss);
    if(lane==0) red[wid] = ss;
    __syncthreads();
    float tot = red[0]+red[1]+red[2]+red[3]+red[4]+red[5]+red[6]+red[7];
    float rs = rsqrtf(tot/(float)H + EPS);
    *(float4*)(hw + tid*4) = make_float4(a.x*rs*wa.x, a.y*rs*wa.y, a.z*rs*wa.z, a.w*rs*wa.w);
    __syncthreads();

    float acc = 0.f;
#pragma unroll
    for(int i=0;i<8;i++){
        float4 rv = *(const float4*)(wlds + wid*2048 + i*256 + lane*4);
        float4 hv = *(const float4*)(hw + i*256 + lane*4);
        acc += rv.x*hv.x + rv.y*hv.y + rv.z*hv.z + rv.w*hv.w;
    }
    acc = wave_sum(acc);
    if(lane==0) *op = acc;
}

// ---------- K2: q/k RMS + RoPE + gate sigmoid. grid 20 x 64 ---------- (unchanged)
__global__ __launch_bounds__(64) void k_rope(const float* __restrict__ qg,
                                             const float* __restrict__ kvec,
                                             const float* __restrict__ vvec,
                                             const int* __restrict__ pos,
                                             const float* __restrict__ qn,
                                             const float* __restrict__ kn,
                                             const float* __restrict__ rc,
                                             const float* __restrict__ rsn,
                                             float* __restrict__ q_rope,
                                             float* __restrict__ gate_sig,
                                             float* __restrict__ knew,
                                             float* __restrict__ vnew){
    int b = blockIdx.x, lane = threadIdx.x;
    int p = pos[0];
    float c = rc[(size_t)p*64 + lane];
    float s = rsn[(size_t)p*64 + lane];
    if(b < NH){
        int h = b;
        float x1 = qg[h*256 + lane], x2 = qg[h*256 + 64 + lane];
        float ssq = wave_sum(x1*x1 + x2*x2);
        float r = rsqrtf(ssq/128.f + EPS);
        float n1 = x1*r*qn[lane];
        float n2 = x2*r*qn[lane+64];
        q_rope[h*128 + lane]      = n1*c - n2*s;
        q_rope[h*128 + 64 + lane] = n2*c + n1*s;
        float g1 = qg[h*256 + 128 + lane], g2 = qg[h*256 + 192 + lane];
        gate_sig[h*128 + lane]      = 1.f/(1.f + __expf(-g1));
        gate_sig[h*128 + 64 + lane] = 1.f/(1.f + __expf(-g2));
    } else {
        int j = b - NH;
        float x1 = kvec[j*128 + lane], x2 = kvec[j*128 + 64 + lane];
        float ssq = wave_sum(x1*x1 + x2*x2);
        float r = rsqrtf(ssq/128.f + EPS);
        float n1 = x1*r*kn[lane];
        float n2 = x2*r*kn[lane+64];
        knew[j*128 + lane]      = n1*c - n2*s;
        knew[j*128 + 64 + lane] = n2*c + n1*s;
        vnew[j*128 + lane]      = vvec[j*128 + lane];
        vnew[j*128 + 64 + lane] = vvec[j*128 + 64 + lane];
    }
}

// ---------- K3: flash-decode partials v2. grid (nchunk, NKV) x 256 ---------- (unchanged)
__global__ __launch_bounds__(256) void k_attn_part(const float* __restrict__ cache,
                                                   const float* __restrict__ q_rope,
                                                   const float* __restrict__ mask,
                                                   const int* __restrict__ pos,
                                                   const float* __restrict__ knew,
                                                   const float* __restrict__ vnew,
                                                   float* __restrict__ part_m,
                                                   float* __restrict__ part_l,
                                                   float* __restrict__ part_o,
                                                   int nchunk, int chunk){
    int j = blockIdx.y, ci = blockIdx.x, tid = threadIdx.x;
    int p = pos[0];
    __shared__ __align__(16) float q_s[512];
    __shared__ float s_s[512];
    __shared__ __align__(16) float V_s[128*128];
    __shared__ float m_s[4], l_s[4], sc_s[4];
    int lane = tid&63, w = tid>>6;
    int base0 = ci*chunk;

    q_s[tid]       = q_rope[j*512 + tid];
    q_s[256 + tid] = q_rope[j*512 + 256 + tid];
    if(tid < 4){ m_s[tid] = -3.0e38f; l_s[tid] = 0.f; }
    float o0=0.f,o1=0.f,o2=0.f,o3=0.f;
    __syncthreads();

    for(int s0=0; s0<chunk; s0+=128){
        if(w >= 2){
            const float* vb = cache + (size_t)NKV*CTX*HD + ((size_t)j*CTX + base0 + s0)*HD;
            int half = w - 2;
#pragma unroll
            for(int i=0;i<32;i++){
                int idx = half*32 + i;
                stage16(vb + idx*256 + lane*4, V_s + idx*256);
            }
        } else {
            int c = base0 + s0 + tid;
            const float* kr = (c==p) ? (knew + (size_t)j*HD)
                                     : (cache + ((size_t)j*CTX + c)*HD);
            float a0=0.f,a1=0.f,a2=0.f,a3=0.f;
            for(int d0=0; d0<HD; d0+=32){
                float4 u8[8];
#pragma unroll
                for(int t=0;t<8;t++) u8[t] = *(const float4*)(kr + d0 + t*4);
#pragma unroll
                for(int t=0;t<8;t++) keep4(u8[t]);
#pragma unroll
                for(int t=0;t<8;t++){
                    int dd = d0 + t*4;
                    const float* q0=q_s+dd; const float* q1=q_s+128+dd;
                    const float* q2=q_s+256+dd; const float* q3=q_s+384+dd;
                    a0 += q0[0]*u8[t].x+q0[1]*u8[t].y+q0[2]*u8[t].z+q0[3]*u8[t].w;
                    a1 += q1[0]*u8[t].x+q1[1]*u8[t].y+q1[2]*u8[t].z+q1[3]*u8[t].w;
                    a2 += q2[0]*u8[t].x+q2[1]*u8[t].y+q2[2]*u8[t].z+q2[3]*u8[t].w;
                    a3 += q3[0]*u8[t].x+q3[1]*u8[t].y+q3[2]*u8[t].z+q3[3]*u8[t].w;
                }
            }
            float mv = mask[c];
            s_s[tid]       = a0*SCALE + mv;
            s_s[128 + tid] = a1*SCALE + mv;
            s_s[256 + tid] = a2*SCALE + mv;
            s_s[384 + tid] = a3*SCALE + mv;
        }
        __syncthreads();

        int prow = p - (base0 + s0);
        if(prow >= 0 && prow < 128 && tid < 128)
            V_s[prow*128 + tid] = vnew[(size_t)j*HD + tid];

        {
            float v0 = s_s[w*128 + lane], v1 = s_s[w*128 + 64 + lane];
            float mt = wave_max(fmaxf(v0, v1));
            float mn = fmaxf(m_s[w], mt);
            float sc = __expf(m_s[w] - mn);
            float w0 = __expf(v0 - mn), w1 = __expf(v1 - mn);
            float lt = wave_sum(w0 + w1);
            s_s[w*128 + lane]      = w0;
            s_s[w*128 + 64 + lane] = w1;
            if(lane==0){ l_s[w] = l_s[w]*sc + lt; m_s[w] = mn; sc_s[w] = sc; }
        }
        __syncthreads();

        o0 *= sc_s[0]; o1 *= sc_s[1]; o2 *= sc_s[2]; o3 *= sc_s[3];
        int d = tid & 127, rh = tid >> 7;
        const float* vbase = V_s + rh*64*128 + d;
        const float* p0 = s_s + rh*64;
#pragma unroll 8
        for(int cc=0; cc<64; cc++){
            float v = vbase[cc*128];
            o0 += p0[cc]*v;
            o1 += p0[128+cc]*v;
            o2 += p0[256+cc]*v;
            o3 += p0[384+cc]*v;
        }
        __syncthreads();
    }

    int d = tid & 127, rh = tid >> 7;
    V_s[rh*512 + 0*128 + d] = o0;
    V_s[rh*512 + 1*128 + d] = o1;
    V_s[rh*512 + 2*128 + d] = o2;
    V_s[rh*512 + 3*128 + d] = o3;
    __syncthreads();
    if(tid < 128){
#pragma unroll
        for(int h=0;h<4;h++){
            float o = V_s[h*128 + tid] + V_s[512 + h*128 + tid];
            part_o[((size_t)(j*4+h)*nchunk + ci)*128 + tid] = o;
        }
    }
    if(tid < 4){
        part_m[(j*4+tid)*nchunk + ci] = m_s[tid];
        part_l[(j*4+tid)*nchunk + ci] = l_s[tid];
    }
}

// ---------- K4: combine chunks + gate. grid 16 x 128 ---------- (unchanged)
__global__ __launch_bounds__(128) void k_attn_red(const float* __restrict__ part_m,
                                                  const float* __restrict__ part_l,
                                                  const float* __restrict__ part_o,
                                                  const float* __restrict__ gate_sig,
                                                  float* __restrict__ attn,
                                                  int nchunk){
    __shared__ float e_s[64];
    __shared__ float lg_s;
    int h = blockIdx.x, tid = threadIdx.x, lane = tid&63, w = tid>>6;
    if(w == 0){
        float pm = (lane < nchunk) ? part_m[h*nchunk + lane] : -3.0e38f;
        float pl = (lane < nchunk) ? part_l[h*nchunk + lane] : 0.f;
        float mg = wave_max(pm);
        float e  = (lane < nchunk) ? __expf(pm - mg) : 0.f;
        float lg = wave_sum(pl * e);
        if(lane < 64) e_s[lane] = e;
        if(lane == 0) lg_s = lg;
    }
    __syncthreads();
    float lg = lg_s;
    float oa = 0.f;
    for(int i=0;i<nchunk;i++)
        oa += e_s[i]*part_o[((size_t)h*nchunk + i)*128 + tid];
    attn[h*128 + tid] = oa/lg * gate_sig[h*128 + tid];
}

// ---------- K5: Wo matvec + residual, counted-vmcnt streamed. grid 256 x 512 ----------
// Each wave consumes ONLY its own staged LDS -> no __syncthreads drain needed.
// 8 act loads + 8 stages all in flight; chunk i consumed after vmcnt(7-i).
__global__ __launch_bounds__(512) void k_wo(const float* __restrict__ Wo,
                                            const float* __restrict__ attn,
                                            const float* __restrict__ resid,
                                            float* __restrict__ x){
    __shared__ __align__(16) float wlds[8*2048];   // 64KB: one row per wave
    int tid = threadIdx.x, wid = tid>>6, lane = tid&63;
    int row = blockIdx.x*8 + wid;
    const float* wr = Wo + (size_t)row*H;
    float4 av[8];
#pragma unroll
    for(int i=0;i<8;i++) av[i] = *(const float4*)(attn + i*256 + lane*4);
#pragma unroll
    for(int i=0;i<8;i++) stage16(wr + i*256 + lane*4, wlds + wid*2048 + i*256);
    const float* wb = wlds + wid*2048 + lane*4;
    float acc = 0.f;
#define WSTEP(I,N) { WV(N); float4 rv = *(const float4*)(wb + I*256); \
                     acc += rv.x*av[I].x + rv.y*av[I].y + rv.z*av[I].z + rv.w*av[I].w; }
    WSTEP(0,7) WSTEP(1,6) WSTEP(2,5) WSTEP(3,4)
    WSTEP(4,3) WSTEP(5,2) WSTEP(6,1) WSTEP(7,0)
#undef WSTEP
    acc = wave_sum(acc);
    if(lane==0) x[row] = resid[row] + acc;
}

// ---------- K6: fused ln2-RMSNorm + gate/up matvec + SiLU. grid 2048 x 256 ----------
// (unchanged control: best measured form, 48.6us)
__global__ __launch_bounds__(256,2) void k_gateup(const float* __restrict__ Wg,
                                                  const float* __restrict__ Wu,
                                                  const float* __restrict__ xres,
                                                  const float* __restrict__ ln2,
                                                  float* __restrict__ act){
    __shared__ __align__(16) float hw[H];
    __shared__ __align__(16) float wlds[4*4096];   // 64KB: g-row + u-row per wave
    __shared__ float red[4];
    int tid = threadIdx.x, wid = tid>>6, lane = tid&63;
    int row = blockIdx.x*4 + wid;
    const float* gr = Wg + (size_t)row*H;
    const float* ur = Wu + (size_t)row*H;
    float4 a = *(const float4*)(xres + (size_t)tid*8);
    float4 b = *(const float4*)(xres + (size_t)tid*8 + 4);
    float4 wa = *(const float4*)(ln2 + (size_t)tid*8);
    float4 wb = *(const float4*)(ln2 + (size_t)tid*8 + 4);
#pragma unroll
    for(int i=0;i<8;i++) stage16(gr + i*256 + lane*4, wlds + wid*4096 + i*256);
#pragma unroll
    for(int i=0;i<8;i++) stage16(ur + i*256 + lane*4, wlds + wid*4096 + 2048 + i*256);

    float x[8] = {a.x,a.y,a.z,a.w,b.x,b.y,b.z,b.w};
    float ss = 0.f;
#pragma unroll
    for(int i=0;i<8;i++) ss += x[i]*x[i];
    ss = wave_sum(ss);
    if(lane==0) red[wid] = ss;
    __syncthreads();
    float tot = red[0]+red[1]+red[2]+red[3];
    float rs = rsqrtf(tot/(float)H + EPS);
    *(float4*)(hw + tid*8)     = make_float4(x[0]*rs*wa.x, x[1]*rs*wa.y, x[2]*rs*wa.z, x[3]*rs*wa.w);
    *(float4*)(hw + tid*8 + 4) = make_float4(x[4]*rs*wb.x, x[5]*rs*wb.y, x[6]*rs*wb.z, x[7]*rs*wb.w);
    __syncthreads();

    float ag = 0.f, au = 0.f;
#pragma unroll
    for(int i=0;i<8;i++){
        float4 gv = *(const float4*)(wlds + wid*4096 + i*256 + lane*4);
        float4 uv = *(const float4*)(wlds + wid*4096 + 2048 + i*256 + lane*4);
        float4 hv = *(const float4*)(hw + i*256 + lane*4);
        ag += gv.x*hv.x + gv.y*hv.y + gv.z*hv.z + gv.w*hv.w;
        au += uv.x*hv.x + uv.y*hv.y + uv.z*hv.z + uv.w*hv.w;
    }
    ag = wave_sum(ag);
    au = wave_sum(au);
    if(lane==0){
        float sg = ag/(1.f + __expf(-ag));
        act[row] = sg*au;
    }
}

// ---------- K7: down matvec + residual, counted-vmcnt streamed. grid 1024 x 256 ----------
// Per-wave LDS region + per-wave counted waits: NO full drain anywhere.
// 16 act loads + 16 stages in flight (24KB/wave); chunk i after vmcnt(15-i).
__global__ __launch_bounds__(256,2) void k_down(const float* __restrict__ Wd,
                                                const float* __restrict__ act,
                                                const float* __restrict__ x,
                                                float* __restrict__ out){
    __shared__ __align__(16) float wlds[4*4096];   // 64KB: 16KB half-row per wave
    __shared__ float part[4];
    int tid = threadIdx.x, wid = tid>>6, lane = tid&63;
    int row  = blockIdx.x*2 + (wid>>1);
    int half = wid&1;
    const float* wr = Wd + (size_t)row*IDIM + half*4096;
    const float* ab = act + half*4096;
    float4 av[16];
#pragma unroll
    for(int i=0;i<16;i++) av[i] = *(const float4*)(ab + i*256 + lane*4);
#pragma unroll
    for(int i=0;i<16;i++) stage16(wr + i*256 + lane*4, wlds + wid*4096 + i*256);
    const float* wb = wlds + wid*4096 + lane*4;
    float acc = 0.f;
#define DSTEP(I,N) { WV(N); float4 rv = *(const float4*)(wb + I*256); \
                     acc += rv.x*av[I].x + rv.y*av[I].y + rv.z*av[I].z + rv.w*av[I].w; }
    DSTEP(0,15)  DSTEP(1,14)  DSTEP(2,13)  DSTEP(3,12)
    DSTEP(4,11)  DSTEP(5,10)  DSTEP(6,9)   DSTEP(7,8)
    DSTEP(8,7)   DSTEP(9,6)   DSTEP(10,5)  DSTEP(11,4)
    DSTEP(12,3)  DSTEP(13,2)  DSTEP(14,1)  DSTEP(15,0)
#undef DSTEP
    acc = wave_sum(acc);
    if(lane==0) part[wid] = acc;
    __syncthreads();
    if(tid < 2){
        int rr = blockIdx.x*2 + tid;
        out[rr] = x[rr] + part[tid*2] + part[tid*2+1];
    }
}

extern "C" void kernel_launch(void* const* d_in, const int* in_sizes, int n_in,
                              void* d_out, int out_size, void* d_ws, size_t ws_size,
                              hipStream_t stream){
    const float* hs   = (const float*)d_in[0];
    const int*   pos  = (const int*)d_in[1];
    const float* mask = (const float*)d_in[2];
    const float* Wq   = (const float*)d_in[3];
    const float* Wk   = (const float*)d_in[4];
    const float* Wv   = (const float*)d_in[5];
    const float* Wo   = (const float*)d_in[6];
    const float* qn   = (const float*)d_in[7];
    const float* kn   = (const float*)d_in[8];
    const float* ln1  = (const float*)d_in[9];
    const float* ln2  = (const float*)d_in[10];
    const float* Wg   = (const float*)d_in[11];
    const float* Wu   = (const float*)d_in[12];
    const float* Wd   = (const float*)d_in[13];
    const float* cache= (const float*)d_in[14];
    const float* rc   = (const float*)d_in[15];
    const float* rsn  = (const float*)d_in[16];
    float* out = (float*)d_out;

    float* ws       = (float*)d_ws;
    float* qg       = ws;                // 4096
    float* kvec     = ws + 4096;         // 512
    float* vvec     = ws + 4608;         // 512
    float* q_rope   = ws + 5120;         // 2048
    float* gate_sig = ws + 7168;         // 2048
    float* xres     = ws + 9216;         // 2048
    float* attn     = ws + 15360;        // 2048
    float* act      = ws + 17408;        // 8192
    float* knew     = ws + 25600;        // 512
    float* vnew     = ws + 26112;        // 512
    int nchunk = 64;
    while(nchunk > 1){
        size_t need = (size_t)(26624 + 2*NH*nchunk + (size_t)NH*nchunk*128) * 4;
        if(need <= ws_size) break;
        nchunk >>= 1;
    }
    int chunk = CTX / nchunk;
    float* part_m = ws + 26624;
    float* part_l = part_m + NH*nchunk;
    float* part_o = part_l + NH*nchunk;

    k_qkv<<<576,512,0,stream>>>(Wq, Wk, Wv, hs, ln1, qg, kvec, vvec);
    k_rope<<<20,64,0,stream>>>(qg, kvec, vvec, pos, qn, kn, rc, rsn, q_rope, gate_sig, knew, vnew);
    dim3 g3(nchunk, NKV);
    k_attn_part<<<g3,256,0,stream>>>(cache, q_rope, mask, pos, knew, vnew,
                                     part_m, part_l, part_o, nchunk, chunk);
    k_attn_red<<<16,128,0,stream>>>(part_m, part_l, part_o, gate_sig, attn, nchunk);
    k_wo<<<256,512,0,stream>>>(Wo, attn, hs, xres);
    k_gateup<<<2048,256,0,stream>>>(Wg, Wu, xres, ln2, act);
    k_down<<<1024,256,0,stream>>>(Wd, act, xres, out);
}